// Round 1
// baseline (221.164 us; speedup 1.0000x reference)
//
#include <hip/hip_runtime.h>
#include <hip/hip_bf16.h>

typedef unsigned short u16;
typedef __attribute__((ext_vector_type(8))) __bf16 bf16x8;
typedef __attribute__((ext_vector_type(4))) float f32x4;

#define GLL16(gptr, lptr) \
  __builtin_amdgcn_global_load_lds((__attribute__((address_space(1))) void*)(gptr), \
                                   (__attribute__((address_space(3))) void*)(lptr), 16, 0, 0)

static __device__ __forceinline__ u16 f2bf(float f) {
  union { float f; unsigned u; } v; v.f = f;
  unsigned r = (v.u + 0x7FFFu + ((v.u >> 16) & 1u)) >> 16;
  return (u16)r;
}

// ---------------- fp32 -> bf16 convert ----------------
__global__ __launch_bounds__(256) void cvt_f32_bf16(const float* __restrict__ in,
                                                    u16* __restrict__ out, int n4) {
  int i = blockIdx.x * blockDim.x + threadIdx.x;
  if (i < n4) {
    float4 v = ((const float4*)in)[i];
    ushort4 o;
    o.x = f2bf(v.x); o.y = f2bf(v.y); o.z = f2bf(v.z); o.w = f2bf(v.w);
    ((ushort4*)out)[i] = o;
  }
}

// ---------------- QKV projection GEMM ----------------
// C[s][f] = sum_e X[s][e] * W[f][e] + bias[f], all bf16 inputs, fp32 acc.
// M=4096 (b*s), N=3072 (3*E), K=1024. Tile 128x128x32, 4 waves.
// Epilogue scatters to Q/K: [B,H,S,D], V: [B,H,D,S] (transposed) in bf16.
__global__ __launch_bounds__(256, 2) void qkv_gemm(
    const u16* __restrict__ xq, const u16* __restrict__ xk, const u16* __restrict__ xv,
    const u16* __restrict__ wbf, const float* __restrict__ bias,
    u16* __restrict__ qout, u16* __restrict__ kout, u16* __restrict__ vtout) {
  __shared__ u16 Al[128 * 32];
  __shared__ u16 Bl[128 * 32];
  const int tid = threadIdx.x;
  const int lane = tid & 63;
  const int w = tid >> 6;
  const int wr = w >> 1, wc = w & 1;
  const int nb = blockIdx.x, mb = blockIdx.y;
  const int row0 = mb * 128;
  const int ncol0 = nb * 128;
  const int which = nb >> 3;  // 0:Q 1:K 2:V
  const u16* A = (which == 0) ? xq : (which == 1) ? xk : xv;
  const u16* Bw = wbf + (size_t)ncol0 * 1024;

  f32x4 acc[4][4];
  f32x4 zero = {0.f, 0.f, 0.f, 0.f};
#pragma unroll
  for (int i = 0; i < 4; i++)
#pragma unroll
    for (int j = 0; j < 4; j++) acc[i][j] = zero;

  const int srow = w * 16 + (lane >> 2);   // staging row (within 64-row pass)
  const int scol = (lane & 3) * 8;         // staging col (elements)

  for (int k0 = 0; k0 < 1024; k0 += 32) {
#pragma unroll
    for (int p = 0; p < 2; p++) {
      const u16* ga = A + (size_t)(row0 + p * 64 + srow) * 1024 + k0 + scol;
      GLL16(ga, &Al[(p * 64 + w * 16) * 32]);
      const u16* gb = Bw + (size_t)(p * 64 + srow) * 1024 + k0 + scol;
      GLL16(gb, &Bl[(p * 64 + w * 16) * 32]);
    }
    __syncthreads();
    bf16x8 af[4], bfr[4];
#pragma unroll
    for (int mi = 0; mi < 4; mi++)
      af[mi] = *(const bf16x8*)&Al[(wr * 64 + mi * 16 + (lane & 15)) * 32 + (lane >> 4) * 8];
#pragma unroll
    for (int ni = 0; ni < 4; ni++)
      bfr[ni] = *(const bf16x8*)&Bl[(wc * 64 + ni * 16 + (lane & 15)) * 32 + (lane >> 4) * 8];
#pragma unroll
    for (int mi = 0; mi < 4; mi++)
#pragma unroll
      for (int ni = 0; ni < 4; ni++)
        acc[mi][ni] = __builtin_amdgcn_mfma_f32_16x16x32_bf16(af[mi], bfr[ni], acc[mi][ni], 0, 0, 0);
    __syncthreads();
  }

  // epilogue: bias + scatter to per-head layouts
#pragma unroll
  for (int mi = 0; mi < 4; mi++) {
    const int rb = row0 + wr * 64 + mi * 16 + (lane >> 4) * 4;
#pragma unroll
    for (int ni = 0; ni < 4; ni++) {
      const int c = ncol0 + wc * 64 + ni * 16 + (lane & 15);
      const float bs = bias[c];
      const int fm = c & 1023;
      const int h = fm >> 6, d = fm & 63;
#pragma unroll
      for (int r = 0; r < 4; r++) {
        const int rr = rb + r;
        const int b = rr >> 11, s = rr & 2047;
        const u16 val = f2bf(acc[mi][ni][r] + bs);
        if (which == 0)
          qout[(((size_t)(b * 16 + h)) * 2048 + s) * 64 + d] = val;
        else if (which == 1)
          kout[(((size_t)(b * 16 + h)) * 2048 + s) * 64 + d] = val;
        else
          vtout[(((size_t)(b * 16 + h)) * 64 + d) * 2048 + s] = val;
      }
    }
  }
}

// ---------------- flash attention ----------------
// grid (bh=32, qtile=32), block 256 (4 waves x 16 q-rows). KV tile 64.
#define PADS 88  // LDS row stride (elems): 176B = 16B-aligned, 2-way bank conflict only
__global__ __launch_bounds__(256, 2) void attn_fwd(
    const u16* __restrict__ qbf, const u16* __restrict__ kbf, const u16* __restrict__ vtbf,
    const float* __restrict__ mask, u16* __restrict__ ctxout) {
  __shared__ u16 Kl[64 * PADS];
  __shared__ u16 Vl[64 * PADS];
  __shared__ u16 Pl[4][16 * PADS];
  const int tid = threadIdx.x, lane = tid & 63, w = tid >> 6;
  const int bh = blockIdx.x, qt = blockIdx.y;
  const int qbase = qt * 64;
  const size_t hbase = (size_t)bh * 2048 * 64;

  // stage Q tile into Kl (reused), read per-wave A-fragments, release
#pragma unroll
  for (int p = 0; p < 2; p++) {
    int idx = p * 256 + tid;
    int row = idx >> 3, c8 = (idx & 7) * 8;
    *(float4*)&Kl[row * PADS + c8] = *(const float4*)&qbf[hbase + (size_t)(qbase + row) * 64 + c8];
  }
  __syncthreads();
  bf16x8 aq0 = *(const bf16x8*)&Kl[(w * 16 + (lane & 15)) * PADS + (lane >> 4) * 8];
  bf16x8 aq1 = *(const bf16x8*)&Kl[(w * 16 + (lane & 15)) * PADS + 32 + (lane >> 4) * 8];
  __syncthreads();

  float m[4], lsum[4];
  f32x4 ctx[4];
  f32x4 zero = {0.f, 0.f, 0.f, 0.f};
#pragma unroll
  for (int r = 0; r < 4; r++) { m[r] = -1e30f; lsum[r] = 0.f; }
#pragma unroll
  for (int d = 0; d < 4; d++) ctx[d] = zero;

  const int qrow0 = qbase + w * 16 + (lane >> 4) * 4;

  for (int t0 = 0; t0 < 2048; t0 += 64) {
    // stage K[64][64] and Vt[64][64]
#pragma unroll
    for (int p = 0; p < 2; p++) {
      int idx = p * 256 + tid;
      int row = idx >> 3, c8 = (idx & 7) * 8;
      *(float4*)&Kl[row * PADS + c8] = *(const float4*)&kbf[hbase + (size_t)(t0 + row) * 64 + c8];
      *(float4*)&Vl[row * PADS + c8] = *(const float4*)&vtbf[hbase + (size_t)row * 2048 + t0 + c8];
    }
    __syncthreads();

    // scores S[16q][64t] per wave
    float s[4][4];
#pragma unroll
    for (int tb = 0; tb < 4; tb++) {
      bf16x8 bk0 = *(const bf16x8*)&Kl[(tb * 16 + (lane & 15)) * PADS + (lane >> 4) * 8];
      bf16x8 bk1 = *(const bf16x8*)&Kl[(tb * 16 + (lane & 15)) * PADS + 32 + (lane >> 4) * 8];
      f32x4 sa = zero;
      sa = __builtin_amdgcn_mfma_f32_16x16x32_bf16(aq0, bk0, sa, 0, 0, 0);
      sa = __builtin_amdgcn_mfma_f32_16x16x32_bf16(aq1, bk1, sa, 0, 0, 0);
      const int tcol = t0 + tb * 16 + (lane & 15);
#pragma unroll
      for (int r = 0; r < 4; r++)
        s[tb][r] = sa[r] * 0.125f + mask[(size_t)(qrow0 + r) * 2048 + tcol];
    }

    // online softmax (per q-row; rows live in (lane>>4, r))
    float alpha[4];
#pragma unroll
    for (int r = 0; r < 4; r++) {
      float rm = fmaxf(fmaxf(s[0][r], s[1][r]), fmaxf(s[2][r], s[3][r]));
      rm = fmaxf(rm, __shfl_xor(rm, 1));
      rm = fmaxf(rm, __shfl_xor(rm, 2));
      rm = fmaxf(rm, __shfl_xor(rm, 4));
      rm = fmaxf(rm, __shfl_xor(rm, 8));
      const float mn = fmaxf(m[r], rm);
      alpha[r] = __expf(m[r] - mn);
      m[r] = mn;
      float ps = 0.f;
#pragma unroll
      for (int tb = 0; tb < 4; tb++) { s[tb][r] = __expf(s[tb][r] - mn); ps += s[tb][r]; }
      ps += __shfl_xor(ps, 1);
      ps += __shfl_xor(ps, 2);
      ps += __shfl_xor(ps, 4);
      ps += __shfl_xor(ps, 8);
      lsum[r] = lsum[r] * alpha[r] + ps;
    }
#pragma unroll
    for (int d = 0; d < 4; d++)
#pragma unroll
      for (int r = 0; r < 4; r++) ctx[d][r] *= alpha[r];

    // P -> LDS (bf16), re-fragment as MFMA A operand
    u16* Pw = Pl[w];
#pragma unroll
    for (int tb = 0; tb < 4; tb++)
#pragma unroll
      for (int r = 0; r < 4; r++)
        Pw[((lane >> 4) * 4 + r) * PADS + tb * 16 + (lane & 15)] = f2bf(s[tb][r]);
    bf16x8 pa0 = *(const bf16x8*)&Pw[(lane & 15) * PADS + (lane >> 4) * 8];
    bf16x8 pa1 = *(const bf16x8*)&Pw[(lane & 15) * PADS + 32 + (lane >> 4) * 8];
#pragma unroll
    for (int d = 0; d < 4; d++) {
      bf16x8 bv0 = *(const bf16x8*)&Vl[(d * 16 + (lane & 15)) * PADS + (lane >> 4) * 8];
      bf16x8 bv1 = *(const bf16x8*)&Vl[(d * 16 + (lane & 15)) * PADS + 32 + (lane >> 4) * 8];
      ctx[d] = __builtin_amdgcn_mfma_f32_16x16x32_bf16(pa0, bv0, ctx[d], 0, 0, 0);
      ctx[d] = __builtin_amdgcn_mfma_f32_16x16x32_bf16(pa1, bv1, ctx[d], 0, 0, 0);
    }
    __syncthreads();
  }

  // finalize: ctx /= l, write bf16 to ctx2 [B*S][E]
  const int b = bh >> 4, h = bh & 15;
#pragma unroll
  for (int r = 0; r < 4; r++) {
    const float inv = 1.f / lsum[r];
    const size_t grow = (size_t)(b * 2048 + qbase + w * 16 + (lane >> 4) * 4 + r) * 1024 + h * 64;
#pragma unroll
    for (int d = 0; d < 4; d++)
      ctxout[grow + d * 16 + (lane & 15)] = f2bf(ctx[d][r] * inv);
  }
}

// ---------------- output projection GEMM ----------------
// out[s][f] = sum_e ctx[s][e] * W[f][e] + bias[f]; fp32 output (d_out).
__global__ __launch_bounds__(256, 2) void proj_gemm(
    const u16* __restrict__ ctx, const u16* __restrict__ wbf,
    const float* __restrict__ bias, float* __restrict__ out) {
  __shared__ u16 Al[128 * 32];
  __shared__ u16 Bl[128 * 32];
  const int tid = threadIdx.x;
  const int lane = tid & 63;
  const int w = tid >> 6;
  const int wr = w >> 1, wc = w & 1;
  const int nb = blockIdx.x, mb = blockIdx.y;
  const int row0 = mb * 128;
  const int ncol0 = nb * 128;
  const u16* Bw = wbf + (size_t)ncol0 * 1024;

  f32x4 acc[4][4];
  f32x4 zero = {0.f, 0.f, 0.f, 0.f};
#pragma unroll
  for (int i = 0; i < 4; i++)
#pragma unroll
    for (int j = 0; j < 4; j++) acc[i][j] = zero;

  const int srow = w * 16 + (lane >> 2);
  const int scol = (lane & 3) * 8;

  for (int k0 = 0; k0 < 1024; k0 += 32) {
#pragma unroll
    for (int p = 0; p < 2; p++) {
      const u16* ga = ctx + (size_t)(row0 + p * 64 + srow) * 1024 + k0 + scol;
      GLL16(ga, &Al[(p * 64 + w * 16) * 32]);
      const u16* gb = Bw + (size_t)(p * 64 + srow) * 1024 + k0 + scol;
      GLL16(gb, &Bl[(p * 64 + w * 16) * 32]);
    }
    __syncthreads();
    bf16x8 af[4], bfr[4];
#pragma unroll
    for (int mi = 0; mi < 4; mi++)
      af[mi] = *(const bf16x8*)&Al[(wr * 64 + mi * 16 + (lane & 15)) * 32 + (lane >> 4) * 8];
#pragma unroll
    for (int ni = 0; ni < 4; ni++)
      bfr[ni] = *(const bf16x8*)&Bl[(wc * 64 + ni * 16 + (lane & 15)) * 32 + (lane >> 4) * 8];
#pragma unroll
    for (int mi = 0; mi < 4; mi++)
#pragma unroll
      for (int ni = 0; ni < 4; ni++)
        acc[mi][ni] = __builtin_amdgcn_mfma_f32_16x16x32_bf16(af[mi], bfr[ni], acc[mi][ni], 0, 0, 0);
    __syncthreads();
  }

#pragma unroll
  for (int mi = 0; mi < 4; mi++) {
    const int rb = row0 + wr * 64 + mi * 16 + (lane >> 4) * 4;
#pragma unroll
    for (int ni = 0; ni < 4; ni++) {
      const int c = ncol0 + wc * 64 + ni * 16 + (lane & 15);
      const float bs = bias[c];
#pragma unroll
      for (int r = 0; r < 4; r++)
        out[(size_t)(rb + r) * 1024 + c] = acc[mi][ni][r] + bs;
    }
  }
}

// ---------------- launch ----------------
extern "C" void kernel_launch(void* const* d_in, const int* in_sizes, int n_in,
                              void* d_out, int out_size, void* d_ws, size_t ws_size,
                              hipStream_t stream) {
  const float* query = (const float*)d_in[0];
  const float* key   = (const float*)d_in[1];
  const float* value = (const float*)d_in[2];
  const float* qkvw  = (const float*)d_in[3];
  const float* qkvb  = (const float*)d_in[4];
  const float* projw = (const float*)d_in[5];
  const float* projb = (const float*)d_in[6];
  const float* mask  = (const float*)d_in[7];

  char* ws = (char*)d_ws;
  // workspace layout (bytes); xq region is reused for ctx after qkv_gemm
  u16* xq    = (u16*)(ws + 0);          // 8 MiB  [4096][1024] bf16 (later: ctx)
  u16* xk    = (u16*)(ws + 8388608);    // 8 MiB
  u16* xv    = (u16*)(ws + 16777216);   // 8 MiB
  u16* wqkv  = (u16*)(ws + 25165824);   // 6 MiB  [3072][1024]
  u16* wproj = (u16*)(ws + 31457280);   // 2 MiB  [1024][1024]
  u16* qb    = (u16*)(ws + 33554432);   // 8 MiB  [B,H,S,D]
  u16* kb    = (u16*)(ws + 41943040);   // 8 MiB  [B,H,S,D]
  u16* vt    = (u16*)(ws + 50331648);   // 8 MiB  [B,H,D,S]
  u16* cx    = xq;                      // ctx [4096][1024] bf16, aliases xq

  cvt_f32_bf16<<<4096, 256, 0, stream>>>(query, xq, 1048576);
  cvt_f32_bf16<<<4096, 256, 0, stream>>>(key, xk, 1048576);
  cvt_f32_bf16<<<4096, 256, 0, stream>>>(value, xv, 1048576);
  cvt_f32_bf16<<<3072, 256, 0, stream>>>(qkvw, wqkv, 786432);
  cvt_f32_bf16<<<1024, 256, 0, stream>>>(projw, wproj, 262144);

  qkv_gemm<<<dim3(24, 32), 256, 0, stream>>>(xq, xk, xv, wqkv, qkvb, qb, kb, vt);
  attn_fwd<<<dim3(32, 32), 256, 0, stream>>>(qb, kb, vt, mask, cx);
  proj_gemm<<<dim3(8, 32), 256, 0, stream>>>(cx, wproj, projb, (float*)d_out);
}

// Round 3
// 184.133 us; speedup vs baseline: 1.2011x; 1.2011x over previous
//
#include <hip/hip_runtime.h>
#include <hip/hip_bf16.h>

typedef unsigned short u16;
typedef __attribute__((ext_vector_type(8))) __bf16 bf16x8;
typedef __attribute__((ext_vector_type(2))) __bf16 bf16x2;
typedef __attribute__((ext_vector_type(4))) float f32x4;

#define LOG2E 1.44269504f

#if __has_builtin(__builtin_amdgcn_exp2f)
#define EXP2F(x) __builtin_amdgcn_exp2f(x)
#else
#define EXP2F(x) __expf((x) * 0.69314718f)
#endif

#define GLL16(gptr, lptr) \
  __builtin_amdgcn_global_load_lds((__attribute__((address_space(1))) void*)(gptr), \
                                   (__attribute__((address_space(3))) void*)(lptr), 16, 0, 0)

static __device__ __forceinline__ u16 f2bf(float f) {
  union { float f; unsigned u; } v; v.f = f;
  unsigned r = (v.u + 0x7FFFu + ((v.u >> 16) & 1u)) >> 16;
  return (u16)r;
}

// ---------------- fp32 -> bf16 convert ----------------
__global__ __launch_bounds__(256) void cvt_f32_bf16(const float* __restrict__ in,
                                                    u16* __restrict__ out, int n4) {
  int i = blockIdx.x * blockDim.x + threadIdx.x;
  if (i < n4) {
    float4 v = ((const float4*)in)[i];
    ushort4 o;
    o.x = f2bf(v.x); o.y = f2bf(v.y); o.z = f2bf(v.z); o.w = f2bf(v.w);
    ((ushort4*)out)[i] = o;
  }
}

// ---------------- mask * log2e (fp32) ----------------
__global__ __launch_bounds__(256) void mask_scale(const float* __restrict__ in,
                                                  float* __restrict__ out, int n4) {
  int i = blockIdx.x * blockDim.x + threadIdx.x;
  if (i < n4) {
    float4 v = ((const float4*)in)[i];
    v.x *= LOG2E; v.y *= LOG2E; v.z *= LOG2E; v.w *= LOG2E;
    ((float4*)out)[i] = v;
  }
}

// ---------------- QKV projection GEMM ----------------
// C[s][f] = sum_e X[s][e] * W[f][e] + bias[f]. Q output pre-scaled by 0.125*log2e.
__global__ __launch_bounds__(256, 2) void qkv_gemm(
    const u16* __restrict__ xq, const u16* __restrict__ xk, const u16* __restrict__ xv,
    const u16* __restrict__ wbf, const float* __restrict__ bias,
    u16* __restrict__ qout, u16* __restrict__ kout, u16* __restrict__ vtout) {
  __shared__ u16 Al[128 * 32];
  __shared__ u16 Bl[128 * 32];
  const int tid = threadIdx.x;
  const int lane = tid & 63;
  const int w = tid >> 6;
  const int wr = w >> 1, wc = w & 1;
  const int nb = blockIdx.x, mb = blockIdx.y;
  const int row0 = mb * 128;
  const int ncol0 = nb * 128;
  const int which = nb >> 3;  // 0:Q 1:K 2:V
  const u16* A = (which == 0) ? xq : (which == 1) ? xk : xv;
  const u16* Bw = wbf + (size_t)ncol0 * 1024;

  f32x4 acc[4][4];
  f32x4 zero = {0.f, 0.f, 0.f, 0.f};
#pragma unroll
  for (int i = 0; i < 4; i++)
#pragma unroll
    for (int j = 0; j < 4; j++) acc[i][j] = zero;

  const int srow = w * 16 + (lane >> 2);
  const int scol = (lane & 3) * 8;

  for (int k0 = 0; k0 < 1024; k0 += 32) {
#pragma unroll
    for (int p = 0; p < 2; p++) {
      const u16* ga = A + (size_t)(row0 + p * 64 + srow) * 1024 + k0 + scol;
      GLL16(ga, &Al[(p * 64 + w * 16) * 32]);
      const u16* gb = Bw + (size_t)(p * 64 + srow) * 1024 + k0 + scol;
      GLL16(gb, &Bl[(p * 64 + w * 16) * 32]);
    }
    __syncthreads();
    bf16x8 af[4], bfr[4];
#pragma unroll
    for (int mi = 0; mi < 4; mi++)
      af[mi] = *(const bf16x8*)&Al[(wr * 64 + mi * 16 + (lane & 15)) * 32 + (lane >> 4) * 8];
#pragma unroll
    for (int ni = 0; ni < 4; ni++)
      bfr[ni] = *(const bf16x8*)&Bl[(wc * 64 + ni * 16 + (lane & 15)) * 32 + (lane >> 4) * 8];
#pragma unroll
    for (int mi = 0; mi < 4; mi++)
#pragma unroll
      for (int ni = 0; ni < 4; ni++)
        acc[mi][ni] = __builtin_amdgcn_mfma_f32_16x16x32_bf16(af[mi], bfr[ni], acc[mi][ni], 0, 0, 0);
    __syncthreads();
  }

#pragma unroll
  for (int mi = 0; mi < 4; mi++) {
    const int rb = row0 + wr * 64 + mi * 16 + (lane >> 4) * 4;
#pragma unroll
    for (int ni = 0; ni < 4; ni++) {
      const int c = ncol0 + wc * 64 + ni * 16 + (lane & 15);
      const float bs = bias[c];
      const float sc = (which == 0) ? (0.125f * LOG2E) : 1.0f;
      const int fm = c & 1023;
      const int h = fm >> 6, d = fm & 63;
#pragma unroll
      for (int r = 0; r < 4; r++) {
        const int rr = rb + r;
        const int b = rr >> 11, s = rr & 2047;
        const u16 val = f2bf((acc[mi][ni][r] + bs) * sc);
        if (which == 0)
          qout[(((size_t)(b * 16 + h)) * 2048 + s) * 64 + d] = val;
        else if (which == 1)
          kout[(((size_t)(b * 16 + h)) * 2048 + s) * 64 + d] = val;
        else
          vtout[(((size_t)(b * 16 + h)) * 64 + d) * 2048 + s] = val;
      }
    }
  }
}

// ---------------- flash attention (swapped-operand, exp2-domain) ----------------
// grid (bh=32, qtile=32), block 256 (4 waves x 16 q). KV tile 64, dbuf + XOR swizzle.
static __device__ __forceinline__ bf16x8 lds_read8(const u16* base, int row, int colB) {
  const char* p = (const char*)base + (row << 7) + (colB ^ ((row & 7) << 4));
  return *(const bf16x8*)p;
}
static __device__ __forceinline__ void lds_write16(u16* base, int row, int colB, float4 v) {
  char* p = (char*)base + (row << 7) + (colB ^ ((row & 7) << 4));
  *(float4*)p = v;
}

__global__ __launch_bounds__(256, 2) void attn_fwd(
    const u16* __restrict__ qbf, const u16* __restrict__ kbf, const u16* __restrict__ vtbf,
    const float* __restrict__ maskS, u16* __restrict__ ctxout) {
  __shared__ u16 lds[20480];  // K0,K1,V0,V1 (4096 elems each) + P 4*1024

  const int tid = threadIdx.x, lane = tid & 63, w = tid >> 6;
  const int qL = lane & 15, g = lane >> 4;
  u16* Pw = lds + 16384 + (w << 10);
  const int bh = blockIdx.x, qt = blockIdx.y;
  const int qbase = qt * 64;
  const size_t hbase = (size_t)bh * 2048 * 64;
  const int qrow = qbase + w * 16 + qL;

  // Q fragments (B-operand: lane holds Q[q=w*16+qL][d=g*8..], pre-scaled)
  bf16x8 q0 = *(const bf16x8*)&qbf[hbase + (size_t)qrow * 64 + g * 8];
  bf16x8 q1 = *(const bf16x8*)&qbf[hbase + (size_t)qrow * 64 + 32 + g * 8];

  // staging: per thread 2x float4 for K and V
  const int srow = tid >> 3;           // 0..31
  const int scol = (tid & 7) * 8;      // elem
  const int scolB = (tid & 7) * 16;    // bytes

  float4 kr0, kr1, vr0, vr1;
  kr0 = *(const float4*)&kbf[hbase + (size_t)srow * 64 + scol];
  kr1 = *(const float4*)&kbf[hbase + (size_t)(32 + srow) * 64 + scol];
  vr0 = *(const float4*)&vtbf[hbase + (size_t)srow * 2048 + scol];
  vr1 = *(const float4*)&vtbf[hbase + (size_t)(32 + srow) * 2048 + scol];
  lds_write16(lds, srow, scolB, kr0);
  lds_write16(lds, 32 + srow, scolB, kr1);
  lds_write16(lds + 8192, srow, scolB, vr0);
  lds_write16(lds + 8192, 32 + srow, scolB, vr1);
  // tile 1 into regs
  kr0 = *(const float4*)&kbf[hbase + (size_t)(64 + srow) * 64 + scol];
  kr1 = *(const float4*)&kbf[hbase + (size_t)(96 + srow) * 64 + scol];
  vr0 = *(const float4*)&vtbf[hbase + (size_t)srow * 2048 + 64 + scol];
  vr1 = *(const float4*)&vtbf[hbase + (size_t)(32 + srow) * 2048 + 64 + scol];
  // mask prefetch tile 0 (also MFMA C-init: c[r] = maskS[t=tb*16+g*4+r][q])
  f32x4 mcur[4], mnext[4];
#pragma unroll
  for (int tb = 0; tb < 4; tb++)
    mcur[tb] = *(const f32x4*)&maskS[(size_t)qrow * 2048 + tb * 16 + g * 4];

  float m = -1e30f, lsum = 0.f;
  f32x4 ctx[4];
  f32x4 zero = {0.f, 0.f, 0.f, 0.f};
#pragma unroll
  for (int db = 0; db < 4; db++) ctx[db] = zero;

  __syncthreads();

  for (int t = 0; t < 32; ++t) {
    const int co = (t & 1) << 12;       // current buffer elem offset
    const int no = ((t + 1) & 1) << 12; // next buffer elem offset
    const u16* Kc = lds + co;
    const u16* Vc = lds + 8192 + co;
    // 1. write staged tile t+1 into other buffer
    if (t < 31) {
      lds_write16(lds + no, srow, scolB, kr0);
      lds_write16(lds + no, 32 + srow, scolB, kr1);
      lds_write16(lds + 8192 + no, srow, scolB, vr0);
      lds_write16(lds + 8192 + no, 32 + srow, scolB, vr1);
    }
    // 2. issue global loads for tile t+2
    if (t < 30) {
      const int tt = (t + 2) * 64;
      kr0 = *(const float4*)&kbf[hbase + (size_t)(tt + srow) * 64 + scol];
      kr1 = *(const float4*)&kbf[hbase + (size_t)(tt + 32 + srow) * 64 + scol];
      vr0 = *(const float4*)&vtbf[hbase + (size_t)srow * 2048 + tt + scol];
      vr1 = *(const float4*)&vtbf[hbase + (size_t)(32 + srow) * 2048 + tt + scol];
    }
    // 3. mask prefetch tile t+1
    if (t < 31) {
#pragma unroll
      for (int tb = 0; tb < 4; tb++)
        mnext[tb] = *(const f32x4*)&maskS[(size_t)qrow * 2048 + (t + 1) * 64 + tb * 16 + g * 4];
    }
    // 4. QK^T (swapped: S'[t][q]), mask as C-init
    f32x4 s[4];
    __builtin_amdgcn_s_setprio(1);
#pragma unroll
    for (int tb = 0; tb < 4; tb++) {
      bf16x8 kf0 = lds_read8(Kc, tb * 16 + qL, g * 16);
      bf16x8 kf1 = lds_read8(Kc, tb * 16 + qL, 64 + g * 16);
      s[tb] = __builtin_amdgcn_mfma_f32_16x16x32_bf16(kf0, q0, mcur[tb], 0, 0, 0);
      s[tb] = __builtin_amdgcn_mfma_f32_16x16x32_bf16(kf1, q1, s[tb], 0, 0, 0);
    }
    __builtin_amdgcn_s_setprio(0);
    // 5. online softmax (log2 domain), defer-max THR=8
    float pm = s[0][0];
#pragma unroll
    for (int tb = 0; tb < 4; tb++)
#pragma unroll
      for (int r = 0; r < 4; r++) pm = fmaxf(pm, s[tb][r]);
    pm = fmaxf(pm, __shfl_xor(pm, 16));
    pm = fmaxf(pm, __shfl_xor(pm, 32));
    if (__any(pm > m + 8.0f)) {
      const float mn = fmaxf(m, pm);
      const float al = EXP2F(m - mn);
      m = mn;
      lsum *= al;
#pragma unroll
      for (int db = 0; db < 4; db++) ctx[db] *= al;
    }
    float ps = 0.f;
#pragma unroll
    for (int tb = 0; tb < 4; tb++)
#pragma unroll
      for (int r = 0; r < 4; r++) {
        const float e = EXP2F(s[tb][r] - m);
        s[tb][r] = e;
        ps += e;
      }
    ps += __shfl_xor(ps, 16);
    ps += __shfl_xor(ps, 32);
    lsum += ps;
    // 6. P -> LDS (bf16, swizzled), re-fragment as PV B-operand
#pragma unroll
    for (int tb = 0; tb < 4; tb++)
#pragma unroll
      for (int rp = 0; rp < 2; rp++) {
        bf16x2 pk;
        pk.x = (__bf16)s[tb][rp * 2];
        pk.y = (__bf16)s[tb][rp * 2 + 1];
        const int tcol = tb * 16 + g * 4 + rp * 2;
        *(bf16x2*)((char*)Pw + (qL << 7) + ((tcol * 2) ^ ((qL & 7) << 4))) = pk;
      }
    bf16x8 pa0 = lds_read8(Pw, qL, g * 16);
    bf16x8 pa1 = lds_read8(Pw, qL, 64 + g * 16);
    // 7. PV (swapped: ctx'[d][q] += Vt[d][t]*P[t][q])
    __builtin_amdgcn_s_setprio(1);
#pragma unroll
    for (int db = 0; db < 4; db++) {
      bf16x8 vf0 = lds_read8(Vc, db * 16 + qL, g * 16);
      bf16x8 vf1 = lds_read8(Vc, db * 16 + qL, 64 + g * 16);
      ctx[db] = __builtin_amdgcn_mfma_f32_16x16x32_bf16(vf0, pa0, ctx[db], 0, 0, 0);
      ctx[db] = __builtin_amdgcn_mfma_f32_16x16x32_bf16(vf1, pa1, ctx[db], 0, 0, 0);
    }
    __builtin_amdgcn_s_setprio(0);
#pragma unroll
    for (int tb = 0; tb < 4; tb++) mcur[tb] = mnext[tb];
    __syncthreads();
  }

  // finalize
  const float inv = 1.0f / lsum;
  const int b = bh >> 4, h = bh & 15;
  u16* orow = ctxout + (size_t)(b * 2048 + qrow) * 1024 + h * 64;
#pragma unroll
  for (int db = 0; db < 4; db++)
#pragma unroll
    for (int rp = 0; rp < 2; rp++) {
      bf16x2 pk;
      pk.x = (__bf16)(ctx[db][rp * 2] * inv);
      pk.y = (__bf16)(ctx[db][rp * 2 + 1] * inv);
      *(bf16x2*)&orow[db * 16 + g * 4 + rp * 2] = pk;
    }
}

// ---------------- output projection GEMM ----------------
__global__ __launch_bounds__(256, 2) void proj_gemm(
    const u16* __restrict__ ctx, const u16* __restrict__ wbf,
    const float* __restrict__ bias, float* __restrict__ out) {
  __shared__ u16 Al[128 * 32];
  __shared__ u16 Bl[128 * 32];
  const int tid = threadIdx.x;
  const int lane = tid & 63;
  const int w = tid >> 6;
  const int wr = w >> 1, wc = w & 1;
  const int nb = blockIdx.x, mb = blockIdx.y;
  const int row0 = mb * 128;
  const int ncol0 = nb * 128;
  const u16* Bw = wbf + (size_t)ncol0 * 1024;

  f32x4 acc[4][4];
  f32x4 zero = {0.f, 0.f, 0.f, 0.f};
#pragma unroll
  for (int i = 0; i < 4; i++)
#pragma unroll
    for (int j = 0; j < 4; j++) acc[i][j] = zero;

  const int srow = w * 16 + (lane >> 2);
  const int scol = (lane & 3) * 8;

  for (int k0 = 0; k0 < 1024; k0 += 32) {
#pragma unroll
    for (int p = 0; p < 2; p++) {
      const u16* ga = ctx + (size_t)(row0 + p * 64 + srow) * 1024 + k0 + scol;
      GLL16(ga, &Al[(p * 64 + w * 16) * 32]);
      const u16* gb = Bw + (size_t)(p * 64 + srow) * 1024 + k0 + scol;
      GLL16(gb, &Bl[(p * 64 + w * 16) * 32]);
    }
    __syncthreads();
    bf16x8 af[4], bfr[4];
#pragma unroll
    for (int mi = 0; mi < 4; mi++)
      af[mi] = *(const bf16x8*)&Al[(wr * 64 + mi * 16 + (lane & 15)) * 32 + (lane >> 4) * 8];
#pragma unroll
    for (int ni = 0; ni < 4; ni++)
      bfr[ni] = *(const bf16x8*)&Bl[(wc * 64 + ni * 16 + (lane & 15)) * 32 + (lane >> 4) * 8];
#pragma unroll
    for (int mi = 0; mi < 4; mi++)
#pragma unroll
      for (int ni = 0; ni < 4; ni++)
        acc[mi][ni] = __builtin_amdgcn_mfma_f32_16x16x32_bf16(af[mi], bfr[ni], acc[mi][ni], 0, 0, 0);
    __syncthreads();
  }

#pragma unroll
  for (int mi = 0; mi < 4; mi++) {
    const int rb = row0 + wr * 64 + mi * 16 + (lane >> 4) * 4;
#pragma unroll
    for (int ni = 0; ni < 4; ni++) {
      const int c = ncol0 + wc * 64 + ni * 16 + (lane & 15);
      const float bs = bias[c];
#pragma unroll
      for (int r = 0; r < 4; r++)
        out[(size_t)(rb + r) * 1024 + c] = acc[mi][ni][r] + bs;
    }
  }
}

// ---------------- launch ----------------
extern "C" void kernel_launch(void* const* d_in, const int* in_sizes, int n_in,
                              void* d_out, int out_size, void* d_ws, size_t ws_size,
                              hipStream_t stream) {
  const float* query = (const float*)d_in[0];
  const float* key   = (const float*)d_in[1];
  const float* value = (const float*)d_in[2];
  const float* qkvw  = (const float*)d_in[3];
  const float* qkvb  = (const float*)d_in[4];
  const float* projw = (const float*)d_in[5];
  const float* projb = (const float*)d_in[6];
  const float* mask  = (const float*)d_in[7];

  char* ws = (char*)d_ws;
  u16* xq    = (u16*)(ws + 0);          // 8 MiB  (later: ctx)
  u16* xk    = (u16*)(ws + 8388608);    // 8 MiB  (later: maskS low half)
  u16* xv    = (u16*)(ws + 16777216);   // 8 MiB  (later: maskS high half)
  u16* wqkv  = (u16*)(ws + 25165824);   // 6 MiB
  u16* wproj = (u16*)(ws + 31457280);   // 2 MiB
  u16* qb    = (u16*)(ws + 33554432);   // 8 MiB  [B,H,S,D] (pre-scaled)
  u16* kb    = (u16*)(ws + 41943040);   // 8 MiB  [B,H,S,D]
  u16* vt    = (u16*)(ws + 50331648);   // 8 MiB  [B,H,D,S]
  float* maskS = (float*)(ws + 8388608); // 16 MiB fp32, written AFTER qkv_gemm
  u16* cx    = xq;                      // ctx bf16, aliases xq

  cvt_f32_bf16<<<4096, 256, 0, stream>>>(query, xq, 1048576);
  cvt_f32_bf16<<<4096, 256, 0, stream>>>(key, xk, 1048576);
  cvt_f32_bf16<<<4096, 256, 0, stream>>>(value, xv, 1048576);
  cvt_f32_bf16<<<3072, 256, 0, stream>>>(qkvw, wqkv, 786432);
  cvt_f32_bf16<<<1024, 256, 0, stream>>>(projw, wproj, 262144);

  qkv_gemm<<<dim3(24, 32), 256, 0, stream>>>(xq, xk, xv, wqkv, qkvb, qb, kb, vt);
  mask_scale<<<4096, 256, 0, stream>>>(mask, maskS, 1048576);
  attn_fwd<<<dim3(32, 32), 256, 0, stream>>>(qb, kb, vt, maskS, cx);
  proj_gemm<<<dim3(8, 32), 256, 0, stream>>>(cx, wproj, projb, (float*)d_out);
}

// Round 5
// 177.755 us; speedup vs baseline: 1.2442x; 1.0359x over previous
//
#include <hip/hip_runtime.h>
#include <hip/hip_bf16.h>

typedef unsigned short u16;
typedef __attribute__((ext_vector_type(8))) __bf16 bf16x8;
typedef __attribute__((ext_vector_type(4))) __bf16 bf16x4;
typedef __attribute__((ext_vector_type(4))) float f32x4;

#define LOG2E 1.44269504f

#if __has_builtin(__builtin_amdgcn_exp2f)
#define EXP2F(x) __builtin_amdgcn_exp2f(x)
#else
#define EXP2F(x) __expf((x) * 0.69314718f)
#endif

#define GLL16(gptr, lptr) \
  __builtin_amdgcn_global_load_lds((__attribute__((address_space(1))) void*)(gptr), \
                                   (__attribute__((address_space(3))) void*)(lptr), 16, 0, 0)

static __device__ __forceinline__ u16 f2bf(float f) {
  union { float f; unsigned u; } v; v.f = f;
  unsigned r = (v.u + 0x7FFFu + ((v.u >> 16) & 1u)) >> 16;
  return (u16)r;
}

// ---------------- fp32 -> bf16 convert ----------------
__global__ __launch_bounds__(256) void cvt_f32_bf16(const float* __restrict__ in,
                                                    u16* __restrict__ out, int n4) {
  int i = blockIdx.x * blockDim.x + threadIdx.x;
  if (i < n4) {
    float4 v = ((const float4*)in)[i];
    ushort4 o;
    o.x = f2bf(v.x); o.y = f2bf(v.y); o.z = f2bf(v.z); o.w = f2bf(v.w);
    ((ushort4*)out)[i] = o;
  }
}

// ---------------- QKV projection GEMM ----------------
// C[s][f] = sum_e X[s][e] * W[f][e] + bias[f]. Q output pre-scaled by 0.125*log2e.
__global__ __launch_bounds__(256, 2) void qkv_gemm(
    const u16* __restrict__ xq, const u16* __restrict__ xk, const u16* __restrict__ xv,
    const u16* __restrict__ wbf, const float* __restrict__ bias,
    u16* __restrict__ qout, u16* __restrict__ kout, u16* __restrict__ vtout) {
  __shared__ u16 Al[128 * 32];
  __shared__ u16 Bl[128 * 32];
  const int tid = threadIdx.x;
  const int lane = tid & 63;
  const int w = tid >> 6;
  const int wr = w >> 1, wc = w & 1;
  const int nb = blockIdx.x, mb = blockIdx.y;
  const int row0 = mb * 128;
  const int ncol0 = nb * 128;
  const int which = nb >> 3;  // 0:Q 1:K 2:V
  const u16* A = (which == 0) ? xq : (which == 1) ? xk : xv;
  const u16* Bw = wbf + (size_t)ncol0 * 1024;

  f32x4 acc[4][4];
  f32x4 zero = {0.f, 0.f, 0.f, 0.f};
#pragma unroll
  for (int i = 0; i < 4; i++)
#pragma unroll
    for (int j = 0; j < 4; j++) acc[i][j] = zero;

  const int srow = w * 16 + (lane >> 2);
  const int scol = (lane & 3) * 8;

  for (int k0 = 0; k0 < 1024; k0 += 32) {
#pragma unroll
    for (int p = 0; p < 2; p++) {
      const u16* ga = A + (size_t)(row0 + p * 64 + srow) * 1024 + k0 + scol;
      GLL16(ga, &Al[(p * 64 + w * 16) * 32]);
      const u16* gb = Bw + (size_t)(p * 64 + srow) * 1024 + k0 + scol;
      GLL16(gb, &Bl[(p * 64 + w * 16) * 32]);
    }
    __syncthreads();
    bf16x8 af[4], bfr[4];
#pragma unroll
    for (int mi = 0; mi < 4; mi++)
      af[mi] = *(const bf16x8*)&Al[(wr * 64 + mi * 16 + (lane & 15)) * 32 + (lane >> 4) * 8];
#pragma unroll
    for (int ni = 0; ni < 4; ni++)
      bfr[ni] = *(const bf16x8*)&Bl[(wc * 64 + ni * 16 + (lane & 15)) * 32 + (lane >> 4) * 8];
#pragma unroll
    for (int mi = 0; mi < 4; mi++)
#pragma unroll
      for (int ni = 0; ni < 4; ni++)
        acc[mi][ni] = __builtin_amdgcn_mfma_f32_16x16x32_bf16(af[mi], bfr[ni], acc[mi][ni], 0, 0, 0);
    __syncthreads();
  }

#pragma unroll
  for (int mi = 0; mi < 4; mi++) {
    const int rb = row0 + wr * 64 + mi * 16 + (lane >> 4) * 4;
#pragma unroll
    for (int ni = 0; ni < 4; ni++) {
      const int c = ncol0 + wc * 64 + ni * 16 + (lane & 15);
      const float bs = bias[c];
      const float sc = (which == 0) ? (0.125f * LOG2E) : 1.0f;
      const int fm = c & 1023;
      const int h = fm >> 6, d = fm & 63;
#pragma unroll
      for (int r = 0; r < 4; r++) {
        const int rr = rb + r;
        const int b = rr >> 11, s = rr & 2047;
        const u16 val = f2bf((acc[mi][ni][r] + bs) * sc);
        if (which == 0)
          qout[(((size_t)(b * 16 + h)) * 2048 + s) * 64 + d] = val;
        else if (which == 1)
          kout[(((size_t)(b * 16 + h)) * 2048 + s) * 64 + d] = val;
        else
          vtout[(((size_t)(b * 16 + h)) * 64 + d) * 2048 + s] = val;
      }
    }
  }
}

// ---------------- flash attention ----------------
// grid (bh=32, qtile=32), block 256 (4 waves x 16 q). KV tile 64, dbuf, XOR swizzle,
// unrolled x2 with precomputed LDS addresses and pointer-bump global loads.
// LDS byte map: K buf0 [0,8192) buf1 [8192,16384); V buf0 [16384,24576) buf1 [24576,32768);
// P per-wave [32768 + w*2048, +2048).
// NOTE: lsum is a per-lane PARTIAL (16 of 64 t per tile); the cross-g reduction
// is deferred to the finalize (valid because m/al are identical across the 4
// g-lanes every tile — pm IS reduced per tile).

#define ATTN_TILE(PAR, MC)                                                         \
  {                                                                                \
    f32x4 s0_, s1_, s2_, s3_;                                                      \
    __builtin_amdgcn_s_setprio(1);                                                 \
    {                                                                              \
      bf16x8 a_, b_;                                                               \
      a_ = *(const bf16x8*)(ldsb + Kr0 + 0 + (PAR));                               \
      b_ = *(const bf16x8*)(ldsb + Kr1 + 0 + (PAR));                               \
      s0_ = __builtin_amdgcn_mfma_f32_16x16x32_bf16(a_, q0, MC[0], 0, 0, 0);       \
      s0_ = __builtin_amdgcn_mfma_f32_16x16x32_bf16(b_, q1, s0_, 0, 0, 0);         \
      a_ = *(const bf16x8*)(ldsb + Kr0 + 2048 + (PAR));                            \
      b_ = *(const bf16x8*)(ldsb + Kr1 + 2048 + (PAR));                            \
      s1_ = __builtin_amdgcn_mfma_f32_16x16x32_bf16(a_, q0, MC[1], 0, 0, 0);       \
      s1_ = __builtin_amdgcn_mfma_f32_16x16x32_bf16(b_, q1, s1_, 0, 0, 0);         \
      a_ = *(const bf16x8*)(ldsb + Kr0 + 4096 + (PAR));                            \
      b_ = *(const bf16x8*)(ldsb + Kr1 + 4096 + (PAR));                            \
      s2_ = __builtin_amdgcn_mfma_f32_16x16x32_bf16(a_, q0, MC[2], 0, 0, 0);       \
      s2_ = __builtin_amdgcn_mfma_f32_16x16x32_bf16(b_, q1, s2_, 0, 0, 0);         \
      a_ = *(const bf16x8*)(ldsb + Kr0 + 6144 + (PAR));                            \
      b_ = *(const bf16x8*)(ldsb + Kr1 + 6144 + (PAR));                            \
      s3_ = __builtin_amdgcn_mfma_f32_16x16x32_bf16(a_, q0, MC[3], 0, 0, 0);       \
      s3_ = __builtin_amdgcn_mfma_f32_16x16x32_bf16(b_, q1, s3_, 0, 0, 0);         \
    }                                                                              \
    __builtin_amdgcn_s_setprio(0);                                                 \
    float pm = fmaxf(fmaxf(fmaxf(fmaxf(s0_[0], s0_[1]), fmaxf(s0_[2], s0_[3])),    \
                           fmaxf(fmaxf(s1_[0], s1_[1]), fmaxf(s1_[2], s1_[3]))),   \
                     fmaxf(fmaxf(fmaxf(s2_[0], s2_[1]), fmaxf(s2_[2], s2_[3])),    \
                           fmaxf(fmaxf(s3_[0], s3_[1]), fmaxf(s3_[2], s3_[3]))));  \
    /* speculative exp with current m; shfl max-reduce overlaps */                 \
    s0_[0] = EXP2F(s0_[0] - m); s0_[1] = EXP2F(s0_[1] - m);                        \
    s0_[2] = EXP2F(s0_[2] - m); s0_[3] = EXP2F(s0_[3] - m);                        \
    s1_[0] = EXP2F(s1_[0] - m); s1_[1] = EXP2F(s1_[1] - m);                        \
    s1_[2] = EXP2F(s1_[2] - m); s1_[3] = EXP2F(s1_[3] - m);                        \
    s2_[0] = EXP2F(s2_[0] - m); s2_[1] = EXP2F(s2_[1] - m);                        \
    s2_[2] = EXP2F(s2_[2] - m); s2_[3] = EXP2F(s2_[3] - m);                        \
    s3_[0] = EXP2F(s3_[0] - m); s3_[1] = EXP2F(s3_[1] - m);                        \
    s3_[2] = EXP2F(s3_[2] - m); s3_[3] = EXP2F(s3_[3] - m);                        \
    float ps = ((s0_[0] + s0_[1]) + (s0_[2] + s0_[3])) +                           \
               ((s1_[0] + s1_[1]) + (s1_[2] + s1_[3])) +                           \
               ((s2_[0] + s2_[1]) + (s2_[2] + s2_[3])) +                           \
               ((s3_[0] + s3_[1]) + (s3_[2] + s3_[3]));                            \
    pm = fmaxf(pm, __shfl_xor(pm, 16));                                            \
    pm = fmaxf(pm, __shfl_xor(pm, 32));                                            \
    if (__any(pm > m + 8.0f)) {  /* rare: fix speculation exactly */               \
      const float mn = fmaxf(m, pm);                                               \
      const float al = EXP2F(m - mn);                                              \
      m = mn; lsum *= al; ps *= al;                                                \
      s0_ *= al; s1_ *= al; s2_ *= al; s3_ *= al;                                  \
      ctx[0] *= al; ctx[1] *= al; ctx[2] *= al; ctx[3] *= al;                      \
    }                                                                              \
    lsum += ps;                                                                    \
    {                                                                              \
      bf16x4 p_;                                                                   \
      p_[0] = (__bf16)s0_[0]; p_[1] = (__bf16)s0_[1];                              \
      p_[2] = (__bf16)s0_[2]; p_[3] = (__bf16)s0_[3];                              \
      *(bf16x4*)(ldsb + Pw0) = p_;                                                 \
      p_[0] = (__bf16)s1_[0]; p_[1] = (__bf16)s1_[1];                              \
      p_[2] = (__bf16)s1_[2]; p_[3] = (__bf16)s1_[3];                              \
      *(bf16x4*)(ldsb + Pw1) = p_;                                                 \
      p_[0] = (__bf16)s2_[0]; p_[1] = (__bf16)s2_[1];                              \
      p_[2] = (__bf16)s2_[2]; p_[3] = (__bf16)s2_[3];                              \
      *(bf16x4*)(ldsb + Pw2) = p_;                                                 \
      p_[0] = (__bf16)s3_[0]; p_[1] = (__bf16)s3_[1];                              \
      p_[2] = (__bf16)s3_[2]; p_[3] = (__bf16)s3_[3];                              \
      *(bf16x4*)(ldsb + Pw3) = p_;                                                 \
    }                                                                              \
    {                                                                              \
      bf16x8 pa0 = *(const bf16x8*)(ldsb + Pr0);                                   \
      bf16x8 pa1 = *(const bf16x8*)(ldsb + Pr1);                                   \
      __builtin_amdgcn_s_setprio(1);                                               \
      bf16x8 v0_, v1_;                                                             \
      v0_ = *(const bf16x8*)(ldsb + Kr0 + 16384 + 0 + (PAR));                      \
      v1_ = *(const bf16x8*)(ldsb + Kr1 + 16384 + 0 + (PAR));                      \
      ctx[0] = __builtin_amdgcn_mfma_f32_16x16x32_bf16(v0_, pa0, ctx[0], 0, 0, 0); \
      ctx[0] = __builtin_amdgcn_mfma_f32_16x16x32_bf16(v1_, pa1, ctx[0], 0, 0, 0); \
      v0_ = *(const bf16x8*)(ldsb + Kr0 + 16384 + 2048 + (PAR));                   \
      v1_ = *(const bf16x8*)(ldsb + Kr1 + 16384 + 2048 + (PAR));                   \
      ctx[1] = __builtin_amdgcn_mfma_f32_16x16x32_bf16(v0_, pa0, ctx[1], 0, 0, 0); \
      ctx[1] = __builtin_amdgcn_mfma_f32_16x16x32_bf16(v1_, pa1, ctx[1], 0, 0, 0); \
      v0_ = *(const bf16x8*)(ldsb + Kr0 + 16384 + 4096 + (PAR));                   \
      v1_ = *(const bf16x8*)(ldsb + Kr1 + 16384 + 4096 + (PAR));                   \
      ctx[2] = __builtin_amdgcn_mfma_f32_16x16x32_bf16(v0_, pa0, ctx[2], 0, 0, 0); \
      ctx[2] = __builtin_amdgcn_mfma_f32_16x16x32_bf16(v1_, pa1, ctx[2], 0, 0, 0); \
      v0_ = *(const bf16x8*)(ldsb + Kr0 + 16384 + 6144 + (PAR));                   \
      v1_ = *(const bf16x8*)(ldsb + Kr1 + 16384 + 6144 + (PAR));                   \
      ctx[3] = __builtin_amdgcn_mfma_f32_16x16x32_bf16(v0_, pa0, ctx[3], 0, 0, 0); \
      ctx[3] = __builtin_amdgcn_mfma_f32_16x16x32_bf16(v1_, pa1, ctx[3], 0, 0, 0); \
      __builtin_amdgcn_s_setprio(0);                                               \
    }                                                                              \
  }

__global__ __launch_bounds__(256, 4) void attn_fwd(
    const u16* __restrict__ qbf, const u16* __restrict__ kbf, const u16* __restrict__ vtbf,
    const float* __restrict__ mask, u16* __restrict__ ctxout) {
  __shared__ u16 lds[20480];
  char* ldsb = (char*)lds;
  const int tid = threadIdx.x, lane = tid & 63, w = tid >> 6;
  const int qL = lane & 15, g = lane >> 4;
  const int x = (qL & 7) << 4;
  const int bh = blockIdx.x, qt = blockIdx.y;
  const int qbase = qt * 64;
  const size_t hbase = (size_t)bh * 2048 * 64;
  const int qrow = qbase + w * 16 + qL;

  // precomputed LDS byte addresses (loop-invariant)
  const int Kr0 = qL * 128 + ((g * 16) ^ x);
  const int Kr1 = qL * 128 + ((g * 16 + 64) ^ x);
  const int Pbase = 32768 + w * 2048;
  const int Pr0 = Pbase + Kr0;
  const int Pr1 = Pbase + Kr1;
  const int Pw0 = Pbase + qL * 128 + (((0 * 32) | (g * 8)) ^ x);
  const int Pw1 = Pbase + qL * 128 + (((1 * 32) | (g * 8)) ^ x);
  const int Pw2 = Pbase + qL * 128 + (((2 * 32) | (g * 8)) ^ x);
  const int Pw3 = Pbase + qL * 128 + (((3 * 32) | (g * 8)) ^ x);
  const int srow = tid >> 3;
  const int scol = (tid & 7) * 8;
  const int S0 = srow * 128 + (((tid & 7) * 16) ^ ((srow & 7) << 4));

  // Q fragments (B-operand; pre-scaled by 0.125*log2e in qkv epilogue)
  bf16x8 q0 = *(const bf16x8*)&qbf[hbase + (size_t)qrow * 64 + g * 8];
  bf16x8 q1 = *(const bf16x8*)&qbf[hbase + (size_t)qrow * 64 + 32 + g * 8];

  // prologue: tile 0 -> LDS buf0, tile 1 -> regs
  float4 kr0, kr1, vr0, vr1;
  kr0 = *(const float4*)&kbf[hbase + (size_t)srow * 64 + scol];
  kr1 = *(const float4*)&kbf[hbase + (size_t)(32 + srow) * 64 + scol];
  vr0 = *(const float4*)&vtbf[hbase + (size_t)srow * 2048 + scol];
  vr1 = *(const float4*)&vtbf[hbase + (size_t)(32 + srow) * 2048 + scol];
  *(float4*)(ldsb + S0) = kr0;
  *(float4*)(ldsb + S0 + 4096) = kr1;
  *(float4*)(ldsb + S0 + 16384) = vr0;
  *(float4*)(ldsb + S0 + 20480) = vr1;
  kr0 = *(const float4*)&kbf[hbase + (size_t)(64 + srow) * 64 + scol];
  kr1 = *(const float4*)&kbf[hbase + (size_t)(96 + srow) * 64 + scol];
  vr0 = *(const float4*)&vtbf[hbase + (size_t)srow * 2048 + 64 + scol];
  vr1 = *(const float4*)&vtbf[hbase + (size_t)(32 + srow) * 2048 + 64 + scol];

  // global stream pointers (tile 2 onward)
  const u16* kpA = kbf + hbase + (size_t)(128 + srow) * 64 + scol;
  const u16* kpB = kbf + hbase + (size_t)(160 + srow) * 64 + scol;
  const u16* vpA = vtbf + hbase + (size_t)srow * 2048 + 128 + scol;
  const u16* vpB = vtbf + hbase + (size_t)(32 + srow) * 2048 + 128 + scol;
  const float* mp = mask + (size_t)qrow * 2048 + g * 4;

  f32x4 mA[4], mB[4];
#pragma unroll
  for (int tb = 0; tb < 4; tb++)
    mA[tb] = (*(const f32x4*)(mp + tb * 16)) * LOG2E;

  float m = 0.f, lsum = 0.f;  // m=0 init is safe: scores bounded, defer-max picks up
  f32x4 ctx[4];
  f32x4 zero = {0.f, 0.f, 0.f, 0.f};
#pragma unroll
  for (int db = 0; db < 4; db++) ctx[db] = zero;

  __syncthreads();

  for (int i = 0; i < 16; ++i) {
    // ---- even tile t=2i (buffer 0) ----
    *(float4*)(ldsb + S0 + 8192) = kr0;   // stage tile 2i+1 -> buf1
    *(float4*)(ldsb + S0 + 12288) = kr1;
    *(float4*)(ldsb + S0 + 24576) = vr0;
    *(float4*)(ldsb + S0 + 28672) = vr1;
    if (i < 15) {                          // load tile 2i+2
      kr0 = *(const float4*)kpA;
      kr1 = *(const float4*)kpB;
      vr0 = *(const float4*)vpA;
      vr1 = *(const float4*)vpB;
      kpA += 4096; kpB += 4096; vpA += 64; vpB += 64;
    }
#pragma unroll
    for (int tb = 0; tb < 4; tb++)         // mask for tile 2i+1
      mB[tb] = (*(const f32x4*)(mp + 64 + tb * 16)) * LOG2E;
    ATTN_TILE(0, mA)
    __syncthreads();

    // ---- odd tile t=2i+1 (buffer 1) ----
    if (i < 15) {
      *(float4*)(ldsb + S0) = kr0;         // stage tile 2i+2 -> buf0
      *(float4*)(ldsb + S0 + 4096) = kr1;
      *(float4*)(ldsb + S0 + 16384) = vr0;
      *(float4*)(ldsb + S0 + 20480) = vr1;
      kr0 = *(const float4*)kpA;           // load tile 2i+3
      kr1 = *(const float4*)kpB;
      vr0 = *(const float4*)vpA;
      vr1 = *(const float4*)vpB;
      kpA += 4096; kpB += 4096; vpA += 64; vpB += 64;
#pragma unroll
      for (int tb = 0; tb < 4; tb++)       // mask for tile 2i+2
        mA[tb] = (*(const f32x4*)(mp + 128 + tb * 16)) * LOG2E;
    }
    ATTN_TILE(8192, mB)
    mp += 128;
    __syncthreads();
  }

  // finalize: reduce per-lane partial lsum across the 4 g-lane groups
  // (valid: m/al history identical across g since pm is reduced every tile)
  lsum += __shfl_xor(lsum, 16);
  lsum += __shfl_xor(lsum, 32);
  const float inv = 1.0f / lsum;
  const int b = bh >> 4, h = bh & 15;
  u16* orow = ctxout + (size_t)(b * 2048 + qrow) * 1024 + h * 64;
#pragma unroll
  for (int db = 0; db < 4; db++) {
    bf16x4 o;
    o[0] = (__bf16)(ctx[db][0] * inv);
    o[1] = (__bf16)(ctx[db][1] * inv);
    o[2] = (__bf16)(ctx[db][2] * inv);
    o[3] = (__bf16)(ctx[db][3] * inv);
    *(bf16x4*)&orow[db * 16 + g * 4] = o;
  }
}

// ---------------- output projection GEMM ----------------
__global__ __launch_bounds__(256, 2) void proj_gemm(
    const u16* __restrict__ ctx, const u16* __restrict__ wbf,
    const float* __restrict__ bias, float* __restrict__ out) {
  __shared__ u16 Al[128 * 32];
  __shared__ u16 Bl[128 * 32];
  const int tid = threadIdx.x;
  const int lane = tid & 63;
  const int w = tid >> 6;
  const int wr = w >> 1, wc = w & 1;
  const int nb = blockIdx.x, mb = blockIdx.y;
  const int row0 = mb * 128;
  const int ncol0 = nb * 128;
  const u16* Bw = wbf + (size_t)ncol0 * 1024;

  f32x4 acc[4][4];
  f32x4 zero = {0.f, 0.f, 0.f, 0.f};
#pragma unroll
  for (int i = 0; i < 4; i++)
#pragma unroll
    for (int j = 0; j < 4; j++) acc[i][j] = zero;

  const int srow = w * 16 + (lane >> 2);
  const int scol = (lane & 3) * 8;

  for (int k0 = 0; k0 < 1024; k0 += 32) {
#pragma unroll
    for (int p = 0; p < 2; p++) {
      const u16* ga = ctx + (size_t)(row0 + p * 64 + srow) * 1024 + k0 + scol;
      GLL16(ga, &Al[(p * 64 + w * 16) * 32]);
      const u16* gb = Bw + (size_t)(p * 64 + srow) * 1024 + k0 + scol;
      GLL16(gb, &Bl[(p * 64 + w * 16) * 32]);
    }
    __syncthreads();
    bf16x8 af[4], bfr[4];
#pragma unroll
    for (int mi = 0; mi < 4; mi++)
      af[mi] = *(const bf16x8*)&Al[(wr * 64 + mi * 16 + (lane & 15)) * 32 + (lane >> 4) * 8];
#pragma unroll
    for (int ni = 0; ni < 4; ni++)
      bfr[ni] = *(const bf16x8*)&Bl[(wc * 64 + ni * 16 + (lane & 15)) * 32 + (lane >> 4) * 8];
#pragma unroll
    for (int mi = 0; mi < 4; mi++)
#pragma unroll
      for (int ni = 0; ni < 4; ni++)
        acc[mi][ni] = __builtin_amdgcn_mfma_f32_16x16x32_bf16(af[mi], bfr[ni], acc[mi][ni], 0, 0, 0);
    __syncthreads();
  }

#pragma unroll
  for (int mi = 0; mi < 4; mi++) {
    const int rb = row0 + wr * 64 + mi * 16 + (lane >> 4) * 4;
#pragma unroll
    for (int ni = 0; ni < 4; ni++) {
      const int c = ncol0 + wc * 64 + ni * 16 + (lane & 15);
      const float bs = bias[c];
#pragma unroll
      for (int r = 0; r < 4; r++)
        out[(size_t)(rb + r) * 1024 + c] = acc[mi][ni][r] + bs;
    }
  }
}

// ---------------- launch ----------------
extern "C" void kernel_launch(void* const* d_in, const int* in_sizes, int n_in,
                              void* d_out, int out_size, void* d_ws, size_t ws_size,
                              hipStream_t stream) {
  const float* query = (const float*)d_in[0];
  const float* key   = (const float*)d_in[1];
  const float* value = (const float*)d_in[2];
  const float* qkvw  = (const float*)d_in[3];
  const float* qkvb  = (const float*)d_in[4];
  const float* projw = (const float*)d_in[5];
  const float* projb = (const float*)d_in[6];
  const float* mask  = (const float*)d_in[7];

  char* ws = (char*)d_ws;
  u16* xq    = (u16*)(ws + 0);          // 8 MiB  (later: ctx)
  u16* xk    = (u16*)(ws + 8388608);    // 8 MiB
  u16* xv    = (u16*)(ws + 16777216);   // 8 MiB
  u16* wqkv  = (u16*)(ws + 25165824);   // 6 MiB
  u16* wproj = (u16*)(ws + 31457280);   // 2 MiB
  u16* qb    = (u16*)(ws + 33554432);   // 8 MiB  [B,H,S,D] (pre-scaled)
  u16* kb    = (u16*)(ws + 41943040);   // 8 MiB  [B,H,S,D]
  u16* vt    = (u16*)(ws + 50331648);   // 8 MiB  [B,H,D,S]
  u16* cx    = xq;                      // ctx bf16, aliases xq

  cvt_f32_bf16<<<4096, 256, 0, stream>>>(query, xq, 1048576);
  cvt_f32_bf16<<<4096, 256, 0, stream>>>(key, xk, 1048576);
  cvt_f32_bf16<<<4096, 256, 0, stream>>>(value, xv, 1048576);
  cvt_f32_bf16<<<3072, 256, 0, stream>>>(qkvw, wqkv, 786432);
  cvt_f32_bf16<<<1024, 256, 0, stream>>>(projw, wproj, 262144);

  qkv_gemm<<<dim3(24, 32), 256, 0, stream>>>(xq, xk, xv, wqkv, qkvb, qb, kb, vt);
  attn_fwd<<<dim3(32, 32), 256, 0, stream>>>(qb, kb, vt, mask, cx);
  proj_gemm<<<dim3(8, 32), 256, 0, stream>>>(cx, wproj, projb, (float*)d_out);
}